// Round 9
// baseline (434.889 us; speedup 1.0000x reference)
//
#include <hip/hip_runtime.h>

typedef __attribute__((ext_vector_type(4))) float f4;
typedef __attribute__((ext_vector_type(4))) float f32x4;
typedef __attribute__((ext_vector_type(8))) __bf16 bf8;
typedef __attribute__((ext_vector_type(8))) unsigned short us8;

#define NB 64
#define LSEQ 40
#define D_DIM 768
#define NPATCH 576
#define SEQ 617
#define K_DIM 768
#define M_DIM (NB * NPATCH)   // 36864
#define GEMM_LDS 131072

static __device__ __forceinline__ unsigned short f2bf(float f) {
    union { float f; unsigned u; } v; v.f = f;
    unsigned r = v.u + 0x7FFFu + ((v.u >> 16) & 1u);
    return (unsigned short)(r >> 16);
}

static __device__ __forceinline__ void gload_lds16(const void* g, void* l) {
    __builtin_amdgcn_global_load_lds(
        (const __attribute__((address_space(1))) unsigned int*)g,
        (__attribute__((address_space(3))) unsigned int*)l,
        16, 0, 0);
}

#define MFMA16(a, b, c) __builtin_amdgcn_mfma_f32_16x16x32_bf16((a), (b), (c), 0, 0, 0)

// ---- prep: convert_w + text rows + CLS/masks, one launch ----
// blocks [0,288): conv_w f32 -> bf16 chunk-swizzled
//        [288,928): text gather+LN+mod
//        [928,1275): CLS rows + masks
__global__ __launch_bounds__(256) void prep_kernel(
    const float* __restrict__ cw, unsigned short* __restrict__ wo,
    const int* __restrict__ ids, const int* __restrict__ tti,
    const float* __restrict__ we, const float* __restrict__ pe,
    const float* __restrict__ tke, const float* __restrict__ g,
    const float* __restrict__ bb, const float* __restrict__ mod,
    const float* __restrict__ cls, const int* __restrict__ am,
    float* __restrict__ out) {
    int blk = blockIdx.x;
    if (blk < 288) {
        int t = blk * 256 + threadIdx.x;   // 73728 chunk-threads
        int cs = t % 96, n = t / 96;
        int blk8 = cs >> 3, c = cs & 7;
        int cl = (blk8 << 3) | (c ^ (n & 7));
        const float* s = cw + (size_t)n * 768 + cl * 8;
        f4 a = *(const f4*)s;
        f4 b = *(const f4*)(s + 4);
        us8 r;
        r[0]=f2bf(a[0]); r[1]=f2bf(a[1]); r[2]=f2bf(a[2]); r[3]=f2bf(a[3]);
        r[4]=f2bf(b[0]); r[5]=f2bf(b[1]); r[6]=f2bf(b[2]); r[7]=f2bf(b[3]);
        *(us8*)(wo + (size_t)n * 768 + cs * 8) = r;
    } else if (blk < 928) {
        int row = (blk - 288) * 4 + (threadIdx.x >> 6);   // 2560 rows
        int lane = threadIdx.x & 63;
        int b = row / 40, l = row % 40;
        const float* wp = we + (size_t)ids[row] * 768;
        const float* pp = pe + l * 768;
        const float* tp = tke + (size_t)tti[row] * 768;
        f4 x[3];
        float s = 0.f, q = 0.f;
#pragma unroll
        for (int j = 0; j < 3; ++j) {
            int d = j * 256 + lane * 4;
            f4 v = *(const f4*)(wp + d);
            f4 v2 = *(const f4*)(pp + d);
            f4 v3 = *(const f4*)(tp + d);
            v = v + v2 + v3;
            x[j] = v;
            s += v[0] + v[1] + v[2] + v[3];
            q += v[0]*v[0] + v[1]*v[1] + v[2]*v[2] + v[3]*v[3];
        }
#pragma unroll
        for (int o = 32; o > 0; o >>= 1) { s += __shfl_xor(s, o); q += __shfl_xor(q, o); }
        float mean = s * (1.0f / 768.0f);
        float var = q * (1.0f / 768.0f) - mean * mean;
        float rstd = rsqrtf(var + 1e-12f);
        float* op = out + ((size_t)b * SEQ + 1 + l) * 768;
#pragma unroll
        for (int j = 0; j < 3; ++j) {
            int d = j * 256 + lane * 4;
            f4 gg = *(const f4*)(g + d);
            f4 bv = *(const f4*)(bb + d);
            f4 mm = *(const f4*)(mod + d);
            f4 r = (x[j] - mean) * rstd * gg + bv + mm;
            *(f4*)(op + d) = r;
        }
    } else {
        int t = (blk - 928) * 256 + threadIdx.x;
        if (t < NB * 768) {
            int b = t / 768, d = t % 768;
            out[(size_t)b * SEQ * 768 + d] = cls[d];
        } else if (t < NB * 768 + NB * SEQ) {
            int i = t - NB * 768;
            int b = i / SEQ, s = i % SEQ;
            float v = 1.0f;
            if (s >= 1 && s <= LSEQ) v = (float)am[b * LSEQ + s - 1];
            out[(size_t)NB * SEQ * 768 + i] = v;
        }
    }
}

// ---- fused patch GEMM: 256x256, BK=64, 8 waves, wave-dephased halves ----
// R7 skeleton (best measured) + anti-convoy: wm=0 waves compute (lo,hi)
// halves, wm=1 waves (hi,lo) -> at any instant ~half the waves ds_read
// while the other half MFMA: LDS port and MFMA pipe overlap instead of
// block-wide alternation. setprio(1) wraps MFMA clusters (T5: pays once
// waves have role diversity). Ledger identical to R7:
// tile t: STAGE_B(t+1)[4] + LOAD_A px(t+2)[8] -> ds_read -> WRITE_A(px
// from t-1; auto vmcnt(12)) -> 64 MFMA -> vmcnt(8) lgkmcnt(0) [B drained,
// px stays in flight across barrier] -> s_barrier.
__global__ __launch_bounds__(512, 2) void gemm_patch(
    const float* __restrict__ px, const __bf16* __restrict__ W,
    const float* __restrict__ conv_b, const float* __restrict__ vis_pos,
    const float* __restrict__ mod, float* __restrict__ out) {
    extern __shared__ __align__(16) char smem[];   // 128 KB
    char* Ab0 = smem;            // A buffers: 256 rows x 128 B
    char* Ab1 = smem + 32768;
    char* Bb0 = smem + 65536;    // B buffers
    char* Bb1 = smem + 98304;

    const int tid = threadIdx.x;
    const int w = tid >> 6, lane = tid & 63;

    // bijective XCD remap: 432 blocks = 8 XCDs * 54
    int lid = blockIdx.x;
    int gwi = (lid & 7) * 54 + (lid >> 3);
    const int tile_n = (gwi % 3) * 256;
    const int tile_m = (gwi / 3) * 256;
    const int wm = w >> 2, wn = w & 3;
    const int wr = wm * 128, wc = wn * 64;

    f32x4 acc[8][4] = {};
    const char* Bb = (const char*)W;
    const int rsel = lane & 15;
    const int hk = lane >> 4;

    // ---- A-staging lane geometry (constant across tiles) ----
    const int arow = tid & 255;          // A-tile row this thread stages
    const int ii0 = tid >> 8;            // half selector
    int agm = tile_m + arow;
    int abimg = agm / 576, ap = agm % 576;
    int aph = ap / 24, apw = ap % 24;
    const float* pxrow = px + (size_t)abimg * 3 * 147456
                            + (size_t)(aph * 16) * 384 + apw * 16;

    f4 aregA[2][4], aregB[2][4];

#define LOAD_A(REG, kt)                                                      \
    {                                                                        \
        int c = (kt) >> 2, i0 = ((kt) & 3) << 2;                             \
        _Pragma("unroll")                                                    \
        for (int rep = 0; rep < 2; ++rep) {                                  \
            int i = i0 + ii0 + rep * 2;                                      \
            const float* s = pxrow + (size_t)c * 147456 + i * 384;           \
            _Pragma("unroll")                                                \
            for (int q = 0; q < 4; ++q) REG[rep][q] = *(const f4*)(s + q*4); \
        }                                                                    \
    }

#define WRITE_A(REG, dst)                                                    \
    {                                                                        \
        _Pragma("unroll")                                                    \
        for (int rep = 0; rep < 2; ++rep) {                                  \
            int ii = ii0 + rep * 2;                                          \
            us8 h0, h1;                                                      \
            _Pragma("unroll")                                                \
            for (int q = 0; q < 2; ++q) {                                    \
                h0[q*4+0]=f2bf(REG[rep][q][0]); h0[q*4+1]=f2bf(REG[rep][q][1]); \
                h0[q*4+2]=f2bf(REG[rep][q][2]); h0[q*4+3]=f2bf(REG[rep][q][3]); \
                h1[q*4+0]=f2bf(REG[rep][q+2][0]); h1[q*4+1]=f2bf(REG[rep][q+2][1]); \
                h1[q*4+2]=f2bf(REG[rep][q+2][2]); h1[q*4+3]=f2bf(REG[rep][q+2][3]); \
            }                                                                \
            int cc0 = ii * 2;                                                \
            *(us8*)((dst) + arow * 128 + ((cc0    ) ^ (arow & 7)) * 16) = h0;\
            *(us8*)((dst) + arow * 128 + ((cc0 + 1) ^ (arow & 7)) * 16) = h1;\
        }                                                                    \
    }

    auto STAGE_B = [&](char* lbase, int kt) {
#pragma unroll
        for (int i = 0; i < 4; ++i) {
            int uoff = (w << 10) + i * 8192;       // wave-uniform
            int loff = uoff + (lane << 4);
            int row = loff >> 7, col = loff & 127;
            gload_lds16(Bb + (size_t)(tile_n + row) * 1536 + kt * 128 + col,
                        lbase + uoff);
        }
    };

#define READ_BF(B0, Bl)                                                      \
    _Pragma("unroll")                                                        \
    for (int ni = 0; ni < 4; ++ni) {                                         \
        int r = wc + ni * 16 + rsel;                                         \
        _Pragma("unroll")                                                    \
        for (int ks = 0; ks < 2; ++ks) {                                     \
            int cst = (ks * 4 + hk) ^ (r & 7);                               \
            B0[ni][ks] = *(const bf8*)((Bl) + r * 128 + cst * 16);           \
        }                                                                    \
    }

#define READ_AF(AF, Ac, HB)                                                  \
    _Pragma("unroll")                                                        \
    for (int mi = 0; mi < 4; ++mi) {                                         \
        int r = wr + (HB) + mi * 16 + rsel;                                  \
        _Pragma("unroll")                                                    \
        for (int ks = 0; ks < 2; ++ks) {                                     \
            int cst = (ks * 4 + hk) ^ (r & 7);                               \
            AF[mi][ks] = *(const bf8*)((Ac) + r * 128 + cst * 16);           \
        }                                                                    \
    }

#define MFMA_HALF(AF, B0, ACCB)                                              \
    __builtin_amdgcn_s_setprio(1);                                           \
    _Pragma("unroll")                                                        \
    for (int mi = 0; mi < 4; ++mi)                                           \
        _Pragma("unroll")                                                    \
        for (int ni = 0; ni < 4; ++ni) {                                     \
            acc[(ACCB)+mi][ni] = MFMA16(AF[mi][0], B0[ni][0], acc[(ACCB)+mi][ni]); \
            acc[(ACCB)+mi][ni] = MFMA16(AF[mi][1], B0[ni][1], acc[(ACCB)+mi][ni]); \
        }                                                                    \
    __builtin_amdgcn_s_setprio(0);

    // ---- prologue ----
    STAGE_B(Bb0, 0);               // 4 loads (oldest)
    LOAD_A(aregA, 0);              // 8 px
    LOAD_A(aregB, 1);              // 8 px (newest)
    WRITE_A(aregA, Ab0);           // auto-wait drains B0 + pxA
    asm volatile("s_waitcnt vmcnt(8) lgkmcnt(0)" ::: "memory");
    __builtin_amdgcn_sched_barrier(0);
    __builtin_amdgcn_s_barrier();
    __builtin_amdgcn_sched_barrier(0);

#define TILE_BODY(t, LR, WR, Ac, Bc, An, Bn)                                 \
    {                                                                        \
        const bool doS = (t) + 1 < 12;                                       \
        const bool doL = (t) + 2 < 12;                                       \
        if (doS) STAGE_B(Bn, (t) + 1);                                       \
        if (doL) LOAD_A(LR, (t) + 2);                                        \
        bf8 b0[4][2], af[4][2];                                              \
        READ_BF(b0, Bc)                                                      \
        if (wm == 0) {                                                       \
            READ_AF(af, Ac, 0)                                               \
            if (doS) WRITE_A(WR, An);                                        \
            MFMA_HALF(af, b0, 0)                                             \
            READ_AF(af, Ac, 64)                                              \
            MFMA_HALF(af, b0, 4)                                             \
        } else {                                                             \
            READ_AF(af, Ac, 64)                                              \
            if (doS) WRITE_A(WR, An);                                        \
            MFMA_HALF(af, b0, 4)                                             \
            READ_AF(af, Ac, 0)                                               \
            MFMA_HALF(af, b0, 0)                                             \
        }                                                                    \
        if ((t) < 11) {                                                      \
            if (doL) { asm volatile("s_waitcnt vmcnt(8) lgkmcnt(0)" ::: "memory"); } \
            else     { asm volatile("s_waitcnt vmcnt(0) lgkmcnt(0)" ::: "memory"); } \
            __builtin_amdgcn_sched_barrier(0);                               \
            __builtin_amdgcn_s_barrier();                                    \
            __builtin_amdgcn_sched_barrier(0);                               \
        }                                                                    \
    }

    for (int tt = 0; tt < 12; tt += 2) {
        TILE_BODY(tt,     aregA, aregB, Ab0, Bb0, Ab1, Bb1)
        TILE_BODY(tt + 1, aregB, aregA, Ab1, Bb1, Ab0, Bb0)
    }
#undef TILE_BODY
#undef LOAD_A
#undef WRITE_A
#undef READ_BF
#undef READ_AF
#undef MFMA_HALF

    // ---- epilogue: hoisted div (8 per thread), per-ni const folds ----
    const int lr = (lane >> 4) * 4;
    const int lc = lane & 15;
    int gnv[4]; float cv[4];
#pragma unroll
    for (int ni = 0; ni < 4; ++ni) {
        gnv[ni] = tile_n + wc + ni * 16 + lc;
        cv[ni] = conv_b[gnv[ni]] + mod[768 + gnv[ni]];
    }
#pragma unroll
    for (int mi = 0; mi < 8; ++mi) {
        int gm0 = tile_m + wr + mi * 16 + lr;
        int bimg0 = gm0 / 576;
        int pp0 = gm0 - bimg0 * 576;
#pragma unroll
        for (int r = 0; r < 4; ++r) {
            int bimg = bimg0, pp2 = pp0 + r;
            if (pp2 >= 576) { bimg++; pp2 -= 576; }
            const float* vp = vis_pos + (size_t)(pp2 + 1) * 768;
            float* op = out + ((size_t)bimg * SEQ + 1 + LSEQ + pp2) * 768;
#pragma unroll
            for (int ni = 0; ni < 4; ++ni)
                op[gnv[ni]] = acc[mi][ni][r] + cv[ni] + vp[gnv[ni]];
        }
    }
}

extern "C" void kernel_launch(void* const* d_in, const int* in_sizes, int n_in,
                              void* d_out, int out_size, void* d_ws, size_t ws_size,
                              hipStream_t stream) {
    const int*   ids  = (const int*)d_in[0];
    const int*   am   = (const int*)d_in[1];
    const int*   tti  = (const int*)d_in[2];
    const float* px   = (const float*)d_in[3];
    const float* we   = (const float*)d_in[5];
    const float* pe   = (const float*)d_in[6];
    const float* tke  = (const float*)d_in[7];
    const float* lng  = (const float*)d_in[8];
    const float* lnb  = (const float*)d_in[9];
    const float* cw   = (const float*)d_in[10];
    const float* cb   = (const float*)d_in[11];
    const float* cls  = (const float*)d_in[12];
    const float* vpos = (const float*)d_in[13];
    const float* mod  = (const float*)d_in[14];
    float* out = (float*)d_out;

    __bf16* Wbf = (__bf16*)d_ws;

    hipFuncSetAttribute((const void*)gemm_patch,
                        hipFuncAttributeMaxDynamicSharedMemorySize, GEMM_LDS);

    prep_kernel<<<1275, 256, 0, stream>>>(cw, (unsigned short*)Wbf, ids, tti,
                                          we, pe, tke, lng, lnb, mod, cls, am, out);
    gemm_patch<<<432, 512, GEMM_LDS, stream>>>(px, Wbf, cb, vpos, mod, out);
}

// Round 10
// 101.587 us; speedup vs baseline: 4.2810x; 4.2810x over previous
//
#include <hip/hip_runtime.h>

typedef __attribute__((ext_vector_type(4))) float f4;
typedef __attribute__((ext_vector_type(4))) float f32x4;
typedef __attribute__((ext_vector_type(8))) __bf16 bf8;
typedef __attribute__((ext_vector_type(8))) unsigned short us8;

#define NB 64
#define LSEQ 40
#define D_DIM 768
#define NPATCH 576
#define SEQ 617
#define K_DIM 768
#define M_DIM (NB * NPATCH)   // 36864
#define GEMM_LDS 131072

static __device__ __forceinline__ unsigned short f2bf(float f) {
    union { float f; unsigned u; } v; v.f = f;
    unsigned r = v.u + 0x7FFFu + ((v.u >> 16) & 1u);
    return (unsigned short)(r >> 16);
}

static __device__ __forceinline__ void gload_lds16(const void* g, void* l) {
    __builtin_amdgcn_global_load_lds(
        (const __attribute__((address_space(1))) unsigned int*)g,
        (__attribute__((address_space(3))) unsigned int*)l,
        16, 0, 0);
}

#define MFMA16(a, b, c) __builtin_amdgcn_mfma_f32_16x16x32_bf16((a), (b), (c), 0, 0, 0)

// ---- prep: convert_w + text rows + CLS/masks, one launch ----
// blocks [0,288): conv_w f32 -> bf16 chunk-swizzled
//        [288,928): text gather+LN+mod
//        [928,1275): CLS rows + masks
__global__ __launch_bounds__(256) void prep_kernel(
    const float* __restrict__ cw, unsigned short* __restrict__ wo,
    const int* __restrict__ ids, const int* __restrict__ tti,
    const float* __restrict__ we, const float* __restrict__ pe,
    const float* __restrict__ tke, const float* __restrict__ g,
    const float* __restrict__ bb, const float* __restrict__ mod,
    const float* __restrict__ cls, const int* __restrict__ am,
    float* __restrict__ out) {
    int blk = blockIdx.x;
    if (blk < 288) {
        int t = blk * 256 + threadIdx.x;   // 73728 chunk-threads
        int cs = t % 96, n = t / 96;
        int blk8 = cs >> 3, c = cs & 7;
        int cl = (blk8 << 3) | (c ^ (n & 7));
        const float* s = cw + (size_t)n * 768 + cl * 8;
        f4 a = *(const f4*)s;
        f4 b = *(const f4*)(s + 4);
        us8 r;
        r[0]=f2bf(a[0]); r[1]=f2bf(a[1]); r[2]=f2bf(a[2]); r[3]=f2bf(a[3]);
        r[4]=f2bf(b[0]); r[5]=f2bf(b[1]); r[6]=f2bf(b[2]); r[7]=f2bf(b[3]);
        *(us8*)(wo + (size_t)n * 768 + cs * 8) = r;
    } else if (blk < 928) {
        int row = (blk - 288) * 4 + (threadIdx.x >> 6);   // 2560 rows
        int lane = threadIdx.x & 63;
        int b = row / 40, l = row % 40;
        const float* wp = we + (size_t)ids[row] * 768;
        const float* pp = pe + l * 768;
        const float* tp = tke + (size_t)tti[row] * 768;
        f4 x[3];
        float s = 0.f, q = 0.f;
#pragma unroll
        for (int j = 0; j < 3; ++j) {
            int d = j * 256 + lane * 4;
            f4 v = *(const f4*)(wp + d);
            f4 v2 = *(const f4*)(pp + d);
            f4 v3 = *(const f4*)(tp + d);
            v = v + v2 + v3;
            x[j] = v;
            s += v[0] + v[1] + v[2] + v[3];
            q += v[0]*v[0] + v[1]*v[1] + v[2]*v[2] + v[3]*v[3];
        }
#pragma unroll
        for (int o = 32; o > 0; o >>= 1) { s += __shfl_xor(s, o); q += __shfl_xor(q, o); }
        float mean = s * (1.0f / 768.0f);
        float var = q * (1.0f / 768.0f) - mean * mean;
        float rstd = rsqrtf(var + 1e-12f);
        float* op = out + ((size_t)b * SEQ + 1 + l) * 768;
#pragma unroll
        for (int j = 0; j < 3; ++j) {
            int d = j * 256 + lane * 4;
            f4 gg = *(const f4*)(g + d);
            f4 bv = *(const f4*)(bb + d);
            f4 mm = *(const f4*)(mod + d);
            f4 r = (x[j] - mean) * rstd * gg + bv + mm;
            *(f4*)(op + d) = r;
        }
    } else {
        int t = (blk - 928) * 256 + threadIdx.x;
        if (t < NB * 768) {
            int b = t / 768, d = t % 768;
            out[(size_t)b * SEQ * 768 + d] = cls[d];
        } else if (t < NB * 768 + NB * SEQ) {
            int i = t - NB * 768;
            int b = i / SEQ, s = i % SEQ;
            float v = 1.0f;
            if (s >= 1 && s <= LSEQ) v = (float)am[b * LSEQ + s - 1];
            out[(size_t)NB * SEQ * 768 + i] = v;
        }
    }
}

// ---- fused patch GEMM: 256x256, BK=64, 8 waves — R7 config (best) ----
// A staged from pixel_values via regs (depth-1, single areg set), B via
// global_load_lds from pre-swizzled bf16 W. Per tile t:
//   LOAD_A px(t+1) + STAGE_B(t+1) -> ds_read frags -> 64 MFMA ->
//   WRITE_A (auto vmcnt wait for px, which had the MFMA phase to land) ->
//   __syncthreads (drains B gload_lds + A ds_writes).
// Race ledger: An/Bn last read at t-1 (before t's entry barrier); areg
// consumed (WRITE_A) before next LOAD_A overwrites; barrier = vmcnt(0)+
// lgkmcnt(0)+s_barrier covers both staging paths.
__global__ __launch_bounds__(512, 2) void gemm_patch(
    const float* __restrict__ px, const __bf16* __restrict__ W,
    const float* __restrict__ conv_b, const float* __restrict__ vis_pos,
    const float* __restrict__ mod, float* __restrict__ out) {
    extern __shared__ __align__(16) char smem[];   // 128 KB
    char* Ab0 = smem;            // A buffers: 256 rows x 128 B
    char* Ab1 = smem + 32768;
    char* Bb0 = smem + 65536;    // B buffers
    char* Bb1 = smem + 98304;

    const int tid = threadIdx.x;
    const int w = tid >> 6, lane = tid & 63;

    // bijective XCD remap: 432 blocks = 8 XCDs * 54
    int lid = blockIdx.x;
    int gwi = (lid & 7) * 54 + (lid >> 3);
    const int tile_n = (gwi % 3) * 256;
    const int tile_m = (gwi / 3) * 256;
    const int wm = w >> 2, wn = w & 3;
    const int wr = wm * 128, wc = wn * 64;

    f32x4 acc[8][4] = {};
    const char* Bb = (const char*)W;
    const int rsel = lane & 15;
    const int hk = lane >> 4;

    // ---- A-staging lane geometry (constant across tiles) ----
    const int arow = tid & 255;          // A-tile row this thread stages
    const int ii0 = tid >> 8;            // half selector
    int agm = tile_m + arow;
    int abimg = agm / 576, ap = agm % 576;
    int aph = ap / 24, apw = ap % 24;
    const float* pxrow = px + (size_t)abimg * 3 * 147456
                            + (size_t)(aph * 16) * 384 + apw * 16;

    f4 areg[2][4];
    auto LOAD_A = [&](int kt) {
        int c = kt >> 2, i0 = (kt & 3) << 2;
#pragma unroll
        for (int rep = 0; rep < 2; ++rep) {
            int i = i0 + ii0 + rep * 2;
            const float* s = pxrow + (size_t)c * 147456 + i * 384;
#pragma unroll
            for (int q = 0; q < 4; ++q) areg[rep][q] = *(const f4*)(s + q * 4);
        }
    };
    auto WRITE_A = [&](char* dst) {
#pragma unroll
        for (int rep = 0; rep < 2; ++rep) {
            int ii = ii0 + rep * 2;
            us8 h0, h1;
#pragma unroll
            for (int q = 0; q < 2; ++q) {
                h0[q*4+0]=f2bf(areg[rep][q][0]); h0[q*4+1]=f2bf(areg[rep][q][1]);
                h0[q*4+2]=f2bf(areg[rep][q][2]); h0[q*4+3]=f2bf(areg[rep][q][3]);
                h1[q*4+0]=f2bf(areg[rep][q+2][0]); h1[q*4+1]=f2bf(areg[rep][q+2][1]);
                h1[q*4+2]=f2bf(areg[rep][q+2][2]); h1[q*4+3]=f2bf(areg[rep][q+2][3]);
            }
            int cc0 = ii * 2;
            *(us8*)(dst + arow * 128 + ((cc0    ) ^ (arow & 7)) * 16) = h0;
            *(us8*)(dst + arow * 128 + ((cc0 + 1) ^ (arow & 7)) * 16) = h1;
        }
    };
    auto STAGE_B = [&](char* lbase, int kt) {
#pragma unroll
        for (int i = 0; i < 4; ++i) {
            int uoff = (w << 10) + i * 8192;       // wave-uniform
            int loff = uoff + (lane << 4);
            int row = loff >> 7, col = loff & 127;
            gload_lds16(Bb + (size_t)(tile_n + row) * 1536 + kt * 128 + col,
                        lbase + uoff);
        }
    };

    // prologue: tile 0
    LOAD_A(0);
    STAGE_B(Bb0, 0);
    WRITE_A(Ab0);            // compiler inserts vmcnt wait for areg
    __syncthreads();         // drains B gload_lds + A ds_writes

    for (int t = 0; t < 12; ++t) {
        char* Ac = (t & 1) ? Ab1 : Ab0;
        char* Bc = (t & 1) ? Bb1 : Bb0;
        char* An = (t & 1) ? Ab0 : Ab1;
        char* Bn = (t & 1) ? Bb0 : Bb1;

        if (t < 11) {
            LOAD_A(t + 1);       // f32 pixel loads -> regs, in flight over MFMAs
            STAGE_B(Bn, t + 1);  // bf16 W -> LDS direct
        }

        bf8 a0[4][2], b0[4][2];
#pragma unroll
        for (int mi = 0; mi < 4; ++mi) {
            int r = wr + mi * 16 + rsel;
#pragma unroll
            for (int ks = 0; ks < 2; ++ks) {
                int cst = (ks * 4 + hk) ^ (r & 7);
                a0[mi][ks] = *(const bf8*)(Ac + r * 128 + cst * 16);
            }
        }
#pragma unroll
        for (int ni = 0; ni < 4; ++ni) {
            int r = wc + ni * 16 + rsel;
#pragma unroll
            for (int ks = 0; ks < 2; ++ks) {
                int cst = (ks * 4 + hk) ^ (r & 7);
                b0[ni][ks] = *(const bf8*)(Bc + r * 128 + cst * 16);
            }
        }
#pragma unroll
        for (int mi = 0; mi < 4; ++mi)
#pragma unroll
            for (int ni = 0; ni < 4; ++ni) {
                acc[mi][ni] = MFMA16(a0[mi][0], b0[ni][0], acc[mi][ni]);
                acc[mi][ni] = MFMA16(a0[mi][1], b0[ni][1], acc[mi][ni]);
            }

        bf8 a1[4][2];
#pragma unroll
        for (int mi = 0; mi < 4; ++mi) {
            int r = wr + 64 + mi * 16 + rsel;
#pragma unroll
            for (int ks = 0; ks < 2; ++ks) {
                int cst = (ks * 4 + hk) ^ (r & 7);
                a1[mi][ks] = *(const bf8*)(Ac + r * 128 + cst * 16);
            }
        }
#pragma unroll
        for (int mi = 0; mi < 4; ++mi)
#pragma unroll
            for (int ni = 0; ni < 4; ++ni) {
                acc[4 + mi][ni] = MFMA16(a1[mi][0], b0[ni][0], acc[4 + mi][ni]);
                acc[4 + mi][ni] = MFMA16(a1[mi][1], b0[ni][1], acc[4 + mi][ni]);
            }

        if (t < 11) {
            WRITE_A(An);         // cvt + swizzled ds_write (after MFMAs)
            __syncthreads();     // vmcnt(0)+lgkmcnt(0)+barrier: all staged
        }
    }

    // ---- epilogue: hoisted div (8 per thread), per-ni const folds ----
    const int lr = (lane >> 4) * 4;
    const int lc = lane & 15;
    int gnv[4]; float cv[4];
#pragma unroll
    for (int ni = 0; ni < 4; ++ni) {
        gnv[ni] = tile_n + wc + ni * 16 + lc;
        cv[ni] = conv_b[gnv[ni]] + mod[768 + gnv[ni]];
    }
#pragma unroll
    for (int mi = 0; mi < 8; ++mi) {
        int gm0 = tile_m + wr + mi * 16 + lr;
        int bimg0 = gm0 / 576;
        int pp0 = gm0 - bimg0 * 576;
#pragma unroll
        for (int r = 0; r < 4; ++r) {
            int bimg = bimg0, pp2 = pp0 + r;
            if (pp2 >= 576) { bimg++; pp2 -= 576; }
            const float* vp = vis_pos + (size_t)(pp2 + 1) * 768;
            float* op = out + ((size_t)bimg * SEQ + 1 + LSEQ + pp2) * 768;
#pragma unroll
            for (int ni = 0; ni < 4; ++ni)
                op[gnv[ni]] = acc[mi][ni][r] + cv[ni] + vp[gnv[ni]];
        }
    }
}

extern "C" void kernel_launch(void* const* d_in, const int* in_sizes, int n_in,
                              void* d_out, int out_size, void* d_ws, size_t ws_size,
                              hipStream_t stream) {
    const int*   ids  = (const int*)d_in[0];
    const int*   am   = (const int*)d_in[1];
    const int*   tti  = (const int*)d_in[2];
    const float* px   = (const float*)d_in[3];
    const float* we   = (const float*)d_in[5];
    const float* pe   = (const float*)d_in[6];
    const float* tke  = (const float*)d_in[7];
    const float* lng  = (const float*)d_in[8];
    const float* lnb  = (const float*)d_in[9];
    const float* cw   = (const float*)d_in[10];
    const float* cb   = (const float*)d_in[11];
    const float* cls  = (const float*)d_in[12];
    const float* vpos = (const float*)d_in[13];
    const float* mod  = (const float*)d_in[14];
    float* out = (float*)d_out;

    __bf16* Wbf = (__bf16*)d_ws;

    hipFuncSetAttribute((const void*)gemm_patch,
                        hipFuncAttributeMaxDynamicSharedMemorySize, GEMM_LDS);

    prep_kernel<<<1275, 256, 0, stream>>>(cw, (unsigned short*)Wbf, ids, tti,
                                          we, pe, tke, lng, lnb, mod, cls, am, out);
    gemm_patch<<<432, 512, GEMM_LDS, stream>>>(px, Wbf, cb, vpos, mod, out);
}